// Round 6
// baseline (911.255 us; speedup 1.0000x reference)
//
#include <hip/hip_runtime.h>

// WindowAttention (Swin-style) on gfx950 — R9 (R8 compile fix).
// R9 = R8 with __exp2f -> __builtin_amdgcn_exp2f (glibc macro clash).
// R8 changes vs R7:
//   * gemm_qkv split into gemm_qk (N tiles 0..7) + gemm_v (N tiles 8..11),
//     identical inner structure, so attn2/gemm_bt surface in rocprof top-5.
//   * attn2 softmax in exp2 domain: combined table pre-scaled by log2(e),
//     QK scale folded -> raw v_exp_f32, no mul in chain.
//   * attn2 deferred normalization: ps holds unnormalized e; 1/s applied at
//     the output store from registers.
// ws layout (bytes): unchanged.

typedef unsigned short u16;
typedef __attribute__((ext_vector_type(8))) short short8;
typedef __attribute__((ext_vector_type(4))) float floatx4;

#define B_WIN 2048
#define SEQ 49
#define DIM 512
#define NHEAD 16
#define HD 32
#define MROWS (B_WIN * SEQ)          // 100352
#define QTOT 51380224u               // 2048*16*49*32 elems (one Q or K plane set)
#define VOFF 102760448u              // elem offset of Vt planes ( = 2*QTOT)

__device__ __forceinline__ u16 f2bf(float x) {
    unsigned u = __float_as_uint(x);
    u += 0x7fffu + ((u >> 16) & 1u);   // RNE
    return (u16)(u >> 16);
}

__device__ __forceinline__ void async_ld16(const void* g, void* l) {
    __builtin_amdgcn_global_load_lds(
        (const __attribute__((address_space(1))) void*)g,
        (__attribute__((address_space(3))) void*)l, 16, 0, 0);
}

// ---------- conversion kernels ----------
__global__ void conv_f32_bf16(const float* __restrict__ in, u16* __restrict__ out, int n4) {
    int id = blockIdx.x * 256 + threadIdx.x;
    if (id >= n4) return;
    float4 v = ((const float4*)in)[id];
    uint2 o;
    o.x = (unsigned)f2bf(v.x) | ((unsigned)f2bf(v.y) << 16);
    o.y = (unsigned)f2bf(v.z) | ((unsigned)f2bf(v.w) << 16);
    *(uint2*)(out + (size_t)id * 4) = o;
}

// in: [512][Cn] f32 (k-major). out: [Cn][512] bf16 (n-major).
__global__ void transpose_conv(const float* __restrict__ in, u16* __restrict__ out, int Cn) {
    int id = blockIdx.x * 256 + threadIdx.x;
    if (id >= Cn * 512) return;
    int k = id & 511;
    int n = id >> 9;
    out[id] = f2bf(in[(size_t)k * Cn + n]);
}

// Fragment-ordered padded combined table, PRE-SCALED BY log2(e) (attn softmax
// runs in exp2 domain). For each (w,h,row), 64 floats where slot l16*4 + j
// holds logit column c = j*16 + l16:
//   c < 49 : (bias_table[rel_idx[row*49+c]][h] + mask[w][row*49+c]) * log2(e)
//   c >= 49: -1e30 (softmax pad)
__global__ void build_combined(const float* __restrict__ mask, const float* __restrict__ bias_table,
                               const int* __restrict__ rel_idx, float* __restrict__ cmb) {
    const float LOG2E = 1.4426950408889634f;
    int id = blockIdx.x * 256 + threadIdx.x;    // 64*16*49*64 = 3,211,264
    if (id >= 64 * 16 * 49 * 64) return;
    int w64 = id & 63;
    int j   = w64 & 3;          // fragment block index
    int l   = w64 >> 2;         // lane l16
    int c   = j * 16 + l;       // logit column
    int t   = id >> 6;
    int row = t % 49;
    int wh  = t / 49;
    int h = wh & 15, w = wh >> 4;
    float v = -1.0e30f;
    if (c < 49) {
        int ij = row * 49 + c;
        v = (bias_table[rel_idx[ij] * NHEAD + h] + mask[(size_t)w * 2401 + ij]) * LOG2E;
    }
    cmb[id] = v;
}

// zero V^T pad region: elems s in [48,64) per (bh, d). gemm_v later rewrites s=48.
__global__ void zero_vpad(u16* __restrict__ qkvp) {
    int id = blockIdx.x * 256 + threadIdx.x;     // 2048*16*32 = 1,048,576
    if (id >= 2048 * 16 * 32) return;
    uint4 z = {0u, 0u, 0u, 0u};
    u16* p = qkvp + VOFF + (size_t)id * 64 + 48; // byte offset 96: 16B aligned
    *(uint4*)p = z;                               // elems 48..55
    *((uint4*)p + 1) = z;                         // elems 56..63
}

// ---------- GEMM1 (split): qkv = x @ qkv_w + b, scattered to per-head planes ----
// NBX = n-tiles in this part, NB8 = NBX*784/8 (XCD chunk), NBASE = n offset,
// ISV = V^T epilogue path. Inner structure = R4 128^2 / 2-block-per-CU.
template<int NBX, int NB8, int NBASE, bool ISV>
__global__ __launch_bounds__(256, 2)
void gemm_qkv_part(const u16* __restrict__ A, const u16* __restrict__ Bt,
                   const float* __restrict__ bias, u16* __restrict__ qkvp) {
    const int K = 512;
    const int tid  = threadIdx.x;
    const int lane = tid & 63, wave = tid >> 6;
    const int quad = lane >> 4, l16 = lane & 15;
    const int wr = wave >> 1, wc = wave & 1;

    // XCD-bijective swizzle: NBX*784 blocks = 8 * NB8.
    const int flat = blockIdx.y * NBX + blockIdx.x;
    const int swz  = (flat & 7) * NB8 + (flat >> 3);
    const int bx = swz % NBX;
    const int by = swz / NBX;
    const int m0 = by * 128, n0 = NBASE + bx * 128;

    // K-loop: As = smem[0..4095], Bs = smem[4096..8191] (each 128x32 u16).
    // Epilogue: whole buffer reused as 128x136 bf16 stage.
    __shared__ u16 smem[128 * 136];
    u16* As = smem;
    u16* Bs = smem + 4096;

    const int f0 = (wave * 2 + 0) * 512 + lane * 8;
    const int f1 = (wave * 2 + 1) * 512 + lane * 8;
    const int r0 = f0 >> 5, c0 = f0 & 31;
    const int r1 = f1 >> 5, c1 = f1 & 31;
    const u16* Ab = A + (size_t)m0 * K;
    const u16* Bb = Bt + (size_t)n0 * K;

    floatx4 acc[4][4] = {};

    for (int kt = 0; kt < K; kt += 32) {
        async_ld16(Ab + (size_t)r0 * K + kt + c0, &As[f0]);
        async_ld16(Ab + (size_t)r1 * K + kt + c1, &As[f1]);
        async_ld16(Bb + (size_t)r0 * K + kt + c0, &Bs[f0]);
        async_ld16(Bb + (size_t)r1 * K + kt + c1, &Bs[f1]);
        __syncthreads();
        short8 af[4], bf[4];
#pragma unroll
        for (int i = 0; i < 4; ++i)
            af[i] = *(const short8*)&As[(wr * 64 + i * 16 + l16) * 32 + quad * 8];
#pragma unroll
        for (int j = 0; j < 4; ++j)
            bf[j] = *(const short8*)&Bs[(wc * 64 + j * 16 + l16) * 32 + quad * 8];
#pragma unroll
        for (int i = 0; i < 4; ++i)
#pragma unroll
            for (int j = 0; j < 4; ++j)
                acc[i][j] = __builtin_amdgcn_mfma_f32_16x16x32_bf16(af[i], bf[j], acc[i][j], 0, 0, 0);
        __syncthreads();
    }

    // ---- epilogue phase A: acc (+bias) -> bf16 into padded LDS stage ----
#pragma unroll
    for (int j = 0; j < 4; ++j) {
        const int col = wc * 64 + j * 16 + l16;
        const float bv = bias[n0 + col];
#pragma unroll
        for (int i = 0; i < 4; ++i)
#pragma unroll
            for (int r = 0; r < 4; ++r) {
                const int row = wr * 64 + i * 16 + quad * 4 + r;
                smem[row * 136 + col] = f2bf(acc[i][j][r] + bv);
            }
    }
    __syncthreads();

    // ---- epilogue phase B: cooperative coalesced writeout ----
    if constexpr (!ISV) {
        // Q or K planes: [bh][49][32]; 16B chunks, 64B-line aligned.
        const int c   = n0 >> 9;
        const int hh0 = (n0 & 511) >> 5;
        u16* base = qkvp + (size_t)c * QTOT;
#pragma unroll
        for (int it = 0; it < 8; ++it) {
            const int idx  = it * 256 + tid;      // 0..2047
            const int row  = idx >> 4;
            const int hb   = (idx >> 2) & 3;
            const int part = idx & 3;
            short8 v = *(const short8*)&smem[row * 136 + hb * 32 + part * 8];
            const int rg = m0 + row;
            const int b2 = (int)((unsigned)rg / 49u);
            const int s  = rg - b2 * 49;
            *(short8*)(base + (size_t)(b2 * 16 + hh0 + hb) * 1568 + s * 32 + part * 8) = v;
        }
    } else {
        // V^T planes: [bh][32 d][64 s]; lanes along s (contiguous dst runs).
        const int hh0 = (n0 - 1024) >> 5;
        u16* base = qkvp + VOFF;
#pragma unroll 16
        for (int it = 0; it < 64; ++it) {
            const int idx = it * 256 + tid;       // 0..16383
            const int col = idx >> 7;             // 0..127 (tile col = head*32+d)
            const int row = idx & 127;
            const u16 v = smem[row * 136 + col];
            const int rg = m0 + row;
            const int b2 = (int)((unsigned)rg / 49u);
            const int s  = rg - b2 * 49;
            const int hh = hh0 + (col >> 5);
            const int d  = col & 31;
            base[(size_t)(b2 * 16 + hh) * 2048 + d * 64 + s] = v;
        }
    }
}

// ---------- GEMM: C[M][N] = A[M][K](bf16) * Bt[N][K]^T + bias (f32 out) ----------
__global__ __launch_bounds__(256, 2)
void gemm_bt(const u16* __restrict__ A, const u16* __restrict__ Bt,
             const float* __restrict__ bias, float* __restrict__ Cout,
             int M, int N, int K) {
    const int tid  = threadIdx.x;
    const int lane = tid & 63, wave = tid >> 6;
    const int quad = lane >> 4, l16 = lane & 15;
    const int wr = wave >> 1, wc = wave & 1;

    // XCD-bijective swizzle (applied when grid divides by 8).
    const int nbx = gridDim.x, nby = gridDim.y;
    const int total = nbx * nby;
    const int flat = blockIdx.y * nbx + blockIdx.x;
    const int swz = ((total & 7) == 0) ? ((flat & 7) * (total >> 3) + (flat >> 3)) : flat;
    const int bx = swz % nbx;
    const int by = swz / nbx;
    const int m0 = by * 128, n0 = bx * 128;

    __shared__ u16 As[128 * 32];
    __shared__ u16 Bs[128 * 32];

    const int f0 = (wave * 2 + 0) * 512 + lane * 8;
    const int f1 = (wave * 2 + 1) * 512 + lane * 8;
    const int r0 = f0 >> 5, c0 = f0 & 31;
    const int r1 = f1 >> 5, c1 = f1 & 31;
    const u16* Ab = A + (size_t)m0 * K;
    const u16* Bb = Bt + (size_t)n0 * K;

    floatx4 acc[4][4] = {};

    for (int kt = 0; kt < K; kt += 32) {
        async_ld16(Ab + (size_t)r0 * K + kt + c0, &As[f0]);
        async_ld16(Ab + (size_t)r1 * K + kt + c1, &As[f1]);
        async_ld16(Bb + (size_t)r0 * K + kt + c0, &Bs[f0]);
        async_ld16(Bb + (size_t)r1 * K + kt + c1, &Bs[f1]);
        __syncthreads();
        short8 af[4], bf[4];
#pragma unroll
        for (int i = 0; i < 4; ++i)
            af[i] = *(const short8*)&As[(wr * 64 + i * 16 + l16) * 32 + quad * 8];
#pragma unroll
        for (int j = 0; j < 4; ++j)
            bf[j] = *(const short8*)&Bs[(wc * 64 + j * 16 + l16) * 32 + quad * 8];
#pragma unroll
        for (int i = 0; i < 4; ++i)
#pragma unroll
            for (int j = 0; j < 4; ++j)
                acc[i][j] = __builtin_amdgcn_mfma_f32_16x16x32_bf16(af[i], bf[j], acc[i][j], 0, 0, 0);
        __syncthreads();
    }

#pragma unroll
    for (int i = 0; i < 4; ++i) {
#pragma unroll
        for (int j = 0; j < 4; ++j) {
            int col = n0 + wc * 64 + j * 16 + l16;
            float bv = bias[col];
#pragma unroll
            for (int r = 0; r < 4; ++r) {
                int row = m0 + wr * 64 + i * 16 + quad * 4 + r;
                Cout[(size_t)row * N + col] = acc[i][j][r] + bv;
            }
        }
    }
}

// ---------- attention: one wave per 2 (b,h) pairs; pipelined; register softmax ----------
__global__ __launch_bounds__(64, 4)
void attn2(const u16* __restrict__ qkvp, const float* __restrict__ cmbp,
           u16* __restrict__ out) {
    const int lane = threadIdx.x;
    const int quad = lane >> 4, l16 = lane & 15;
    const int p0 = blockIdx.x * 2;                 // pairs p0, p0+1 (same b)
    const int b  = p0 >> 4, h0 = p0 & 15;

    const u16* qb0 = qkvp + (size_t)p0 * 1568;
    const u16* kb0 = qb0 + QTOT;
    const u16* qb1 = qb0 + 1568;
    const u16* kb1 = kb0 + 1568;
    const u16* vb0 = qkvp + VOFF + (size_t)p0 * 2048;   // V^T [32][64]
    const u16* vb1 = vb0 + 2048;

    const float* cb0 = cmbp + (size_t)(((b & 63) * 16 + h0) * 49) * 64;
    const float* cb1 = cb0 + 49 * 64;

    u16* op0 = out + (size_t)b * SEQ * DIM + h0 * HD;
    u16* op1 = op0 + HD;

    __shared__ u16 ps[64 * 72];        // probs (unnormalized e), row stride 72

    int rr[4];
#pragma unroll
    for (int i = 0; i < 4; ++i) { int r = i * 16 + l16; rr[i] = r > 48 ? 48 : r; }

    // issue Q/K for both pairs up front — pair-1 latency hides under pair-0 work
    short8 af0[4], bf0[4], af1[4], bf1[4];
#pragma unroll
    for (int i = 0; i < 4; ++i) af0[i] = *(const short8*)(qb0 + rr[i] * 32 + quad * 8);
#pragma unroll
    for (int j = 0; j < 4; ++j) bf0[j] = *(const short8*)(kb0 + rr[j] * 32 + quad * 8);
#pragma unroll
    for (int i = 0; i < 4; ++i) af1[i] = *(const short8*)(qb1 + rr[i] * 32 + quad * 8);
#pragma unroll
    for (int j = 0; j < 4; ++j) bf1[j] = *(const short8*)(kb1 + rr[j] * 32 + quad * 8);

    // exp2-domain scale: 32^-0.5 * log2(e)
    const float scale2 = 0.2550348754f;

    auto do_pair = [&](const short8* af, const short8* bfr, const float* cb,
                       const u16* vb, u16* op) {
        // V loads issued first: latency hides under QK^T + softmax
        short8 vf[2][2];
#pragma unroll
        for (int kt = 0; kt < 2; ++kt)
#pragma unroll
            for (int jn = 0; jn < 2; ++jn)
                vf[kt][jn] = *(const short8*)(vb + (jn * 16 + l16) * 64 + kt * 32 + quad * 8);

        float sinv[4][4];                       // 1/rowsum, applied at store

#pragma unroll
        for (int i = 0; i < 4; ++i) {
            floatx4 accS[4] = {};
#pragma unroll
            for (int j = 0; j < 4; ++j)
                accS[j] = __builtin_amdgcn_mfma_f32_16x16x32_bf16(af[i], bfr[j], accS[j], 0, 0, 0);
            const int rbase = i * 16 + quad * 4;
#pragma unroll
            for (int r = 0; r < 4; ++r) {
                const int row = rbase + r;
                const int rc = row < 48 ? row : 48;
                // fragment-ordered table (pre-scaled by log2e): float4 at l16*4
                // = cols {l16, 16+l16, 32+l16, 48+l16}
                float4 c4 = *(const float4*)(cb + rc * 64 + l16 * 4);
                float x[4] = { accS[0][r] * scale2 + c4.x, accS[1][r] * scale2 + c4.y,
                               accS[2][r] * scale2 + c4.z, accS[3][r] * scale2 + c4.w };
                float m = fmaxf(fmaxf(x[0], x[1]), fmaxf(x[2], x[3]));
#pragma unroll
                for (int off = 1; off < 16; off <<= 1) m = fmaxf(m, __shfl_xor(m, off));
                float e[4], s = 0.f;
#pragma unroll
                for (int j = 0; j < 4; ++j) { e[j] = __builtin_amdgcn_exp2f(x[j] - m); s += e[j]; }
#pragma unroll
                for (int off = 1; off < 16; off <<= 1) s += __shfl_xor(s, off);
                sinv[i][r] = __builtin_amdgcn_rcpf(s);
#pragma unroll
                for (int j = 0; j < 4; ++j)
                    ps[row * 72 + j * 16 + l16] = f2bf(e[j]);   // unnormalized
            }
        }
        __syncthreads();   // single wave: cheap; orders ds_write -> ds_read

        // PV: O[64x32] = E[64x64] * V[64x32] via A=ps rows, B=V^T rows
        floatx4 accO[4][2] = {};
#pragma unroll
        for (int kt = 0; kt < 2; ++kt) {
            short8 pf[4];
#pragma unroll
            for (int i = 0; i < 4; ++i)
                pf[i] = *(const short8*)&ps[(i * 16 + l16) * 72 + kt * 32 + quad * 8];
#pragma unroll
            for (int i = 0; i < 4; ++i)
#pragma unroll
                for (int jn = 0; jn < 2; ++jn)
                    accO[i][jn] = __builtin_amdgcn_mfma_f32_16x16x32_bf16(pf[i], vf[kt][jn], accO[i][jn], 0, 0, 0);
        }
        __syncthreads();   // protect ps reuse by next pair

#pragma unroll
        for (int i = 0; i < 4; ++i)
#pragma unroll
            for (int r = 0; r < 4; ++r) {
                const int row = i * 16 + quad * 4 + r;
                if (row < SEQ) {
                    const float inv = sinv[i][r];
#pragma unroll
                    for (int jn = 0; jn < 2; ++jn)
                        op[(size_t)row * DIM + jn * 16 + l16] = f2bf(accO[i][jn][r] * inv);
                }
            }
    };

    do_pair(af0, bf0, cb0, vb0, op0);
    do_pair(af1, bf1, cb1, vb1, op1);
}

extern "C" void kernel_launch(void* const* d_in, const int* in_sizes, int n_in,
                              void* d_out, int out_size, void* d_ws, size_t ws_size,
                              hipStream_t stream) {
    const float* x         = (const float*)d_in[0];
    const float* mask      = (const float*)d_in[1];
    const float* qkv_w     = (const float*)d_in[2];
    const float* qkv_b     = (const float*)d_in[3];
    const float* proj_w    = (const float*)d_in[4];
    const float* proj_b    = (const float*)d_in[5];
    const float* bias_tab  = (const float*)d_in[6];
    const int*   rel_idx   = (const int*)d_in[7];
    float* out = (float*)d_out;

    char* ws = (char*)d_ws;
    u16*   xbf     = (u16*)(ws + 0);               // reused as attn_out
    u16*   qkvp    = (u16*)(ws + 102760448);
    u16*   wqkv_t  = (u16*)(ws + 452333568);
    u16*   wproj_t = (u16*)(ws + 453906432);
    // fragment-ordered padded combined table lives in d_out (scratch until gemm_bt):
    float* cmb     = out;                          // 64*16*49*64 f32 = 12.8 MB

    // x -> bf16 (51,380,224 elems = 12,845,056 float4s)
    conv_f32_bf16<<<50176, 256, 0, stream>>>(x, xbf, 12845056);
    // weight transposes
    transpose_conv<<<3072, 256, 0, stream>>>(qkv_w, wqkv_t, 1536);
    transpose_conv<<<1024, 256, 0, stream>>>(proj_w, wproj_t, 512);
    // fragment-ordered padded combined bias+mask table (x log2e) -> d_out scratch
    build_combined<<<12544, 256, 0, stream>>>(mask, bias_tab, rel_idx, cmb);
    // zero V^T pad rows (s in [48,64)) before gemm_v rewrites s=48
    zero_vpad<<<4096, 256, 0, stream>>>(qkvp);
    // qkv GEMM, split into Q/K-plane and V-plane parts
    gemm_qkv_part<8, 784, 0,    false><<<dim3(8, 784), 256, 0, stream>>>(xbf, wqkv_t, qkv_b, qkvp);
    gemm_qkv_part<4, 392, 1024, true ><<<dim3(4, 784), 256, 0, stream>>>(xbf, wqkv_t, qkv_b, qkvp);
    // attention (2 pairs per wave) -> attn_out (reuses xbf)
    attn2<<<B_WIN * NHEAD / 2, 64, 0, stream>>>(qkvp, cmb, xbf);
    // out = attn @ proj_w + proj_b (overwrites the cmb scratch)
    gemm_bt<<<dim3(4, 784), 256, 0, stream>>>(xbf, wproj_t, proj_b, out,
                                              MROWS, 512, 512);
}

// Round 7
// 855.160 us; speedup vs baseline: 1.0656x; 1.0656x over previous
//
#include <hip/hip_runtime.h>

// WindowAttention (Swin-style) on gfx950 — R10.
// R10 changes vs R9:
//   * gemm_qkv re-merged into one dispatch (R7 structure; R9 split cost ~55us
//     in A re-fetch; it served its observability purpose).
//   * attn2 rewritten: swapped QK^T (mfma(K,Q) -> S^T), softmax fully
//     in-register (lane l16 owns query row j*16+l16; 2 shuffles/row instead
//     of 8; no LDS ps, no barriers). P normalized at bf16 pack; PV A-frags
//     assembled via 16 __shfl per j (parallel batch).
//   * cmb table: natural [w][h][49][64] layout (pad cols -1e30, pre-scaled by
//     log2e) — matches the swapped fragment's per-lane float4 reads.
//   * both pairs' outputs kept packed in regs and stored together at the end
//     -> each 128B output line written once (was 2x line writes).
// ws layout (bytes): unchanged.

typedef unsigned short u16;
typedef __attribute__((ext_vector_type(8))) short short8;
typedef __attribute__((ext_vector_type(4))) float floatx4;
typedef __attribute__((ext_vector_type(4))) unsigned u32x4;

#define B_WIN 2048
#define SEQ 49
#define DIM 512
#define NHEAD 16
#define HD 32
#define MROWS (B_WIN * SEQ)          // 100352
#define QTOT 51380224u               // 2048*16*49*32 elems (one Q or K plane set)
#define VOFF 102760448u              // elem offset of Vt planes ( = 2*QTOT)

__device__ __forceinline__ u16 f2bf(float x) {
    unsigned u = __float_as_uint(x);
    u += 0x7fffu + ((u >> 16) & 1u);   // RNE
    return (u16)(u >> 16);
}

__device__ __forceinline__ void async_ld16(const void* g, void* l) {
    __builtin_amdgcn_global_load_lds(
        (const __attribute__((address_space(1))) void*)g,
        (__attribute__((address_space(3))) void*)l, 16, 0, 0);
}

// ---------- conversion kernels ----------
__global__ void conv_f32_bf16(const float* __restrict__ in, u16* __restrict__ out, int n4) {
    int id = blockIdx.x * 256 + threadIdx.x;
    if (id >= n4) return;
    float4 v = ((const float4*)in)[id];
    uint2 o;
    o.x = (unsigned)f2bf(v.x) | ((unsigned)f2bf(v.y) << 16);
    o.y = (unsigned)f2bf(v.z) | ((unsigned)f2bf(v.w) << 16);
    *(uint2*)(out + (size_t)id * 4) = o;
}

// in: [512][Cn] f32 (k-major). out: [Cn][512] bf16 (n-major).
__global__ void transpose_conv(const float* __restrict__ in, u16* __restrict__ out, int Cn) {
    int id = blockIdx.x * 256 + threadIdx.x;
    if (id >= Cn * 512) return;
    int k = id & 511;
    int n = id >> 9;
    out[id] = f2bf(in[(size_t)k * Cn + n]);
}

// Natural-layout padded combined table, pre-scaled by log2(e):
// cmb[w][h][row 0..48][col 0..63]:
//   col < 49 : (bias_table[rel_idx[row*49+col]][h] + mask[w][row*49+col]) * log2e
//   col >= 49: -1e30 (softmax pad)
__global__ void build_combined(const float* __restrict__ mask, const float* __restrict__ bias_table,
                               const int* __restrict__ rel_idx, float* __restrict__ cmb) {
    const float LOG2E = 1.4426950408889634f;
    int id = blockIdx.x * 256 + threadIdx.x;    // 64*16*49*64 = 3,211,264
    if (id >= 64 * 16 * 49 * 64) return;
    int col = id & 63;
    int t   = id >> 6;
    int row = t % 49;
    int wh  = t / 49;
    int h = wh & 15, w = wh >> 4;
    float v = -1.0e30f;
    if (col < 49) {
        int ij = row * 49 + col;
        v = (bias_table[rel_idx[ij] * NHEAD + h] + mask[(size_t)w * 2401 + ij]) * LOG2E;
    }
    cmb[id] = v;
}

// zero V^T pad region: elems s in [48,64) per (bh, d). gemm_qkv later rewrites s=48.
__global__ void zero_vpad(u16* __restrict__ qkvp) {
    int id = blockIdx.x * 256 + threadIdx.x;     // 2048*16*32 = 1,048,576
    if (id >= 2048 * 16 * 32) return;
    uint4 z = {0u, 0u, 0u, 0u};
    u16* p = qkvp + VOFF + (size_t)id * 64 + 48; // byte offset 96: 16B aligned
    *(uint4*)p = z;                               // elems 48..55
    *((uint4*)p + 1) = z;                         // elems 56..63
}

// ---------- GEMM1: qkv = x @ qkv_w + b, scattered to per-head planes ----------
__global__ __launch_bounds__(256, 2)
void gemm_qkv(const u16* __restrict__ A, const u16* __restrict__ Bt,
              const float* __restrict__ bias, u16* __restrict__ qkvp) {
    const int K = 512;
    const int tid  = threadIdx.x;
    const int lane = tid & 63, wave = tid >> 6;
    const int quad = lane >> 4, l16 = lane & 15;
    const int wr = wave >> 1, wc = wave & 1;

    // XCD-bijective swizzle: 9408 blocks = 8 * 1176.
    const int flat = blockIdx.y * 12 + blockIdx.x;
    const int swz  = (flat & 7) * 1176 + (flat >> 3);
    const int bx = swz % 12;
    const int by = swz / 12;
    const int m0 = by * 128, n0 = bx * 128;

    // K-loop: As = smem[0..4095], Bs = smem[4096..8191] (each 128x32 u16).
    // Epilogue: whole buffer reused as 128x136 bf16 stage.
    __shared__ u16 smem[128 * 136];
    u16* As = smem;
    u16* Bs = smem + 4096;

    const int f0 = (wave * 2 + 0) * 512 + lane * 8;
    const int f1 = (wave * 2 + 1) * 512 + lane * 8;
    const int r0 = f0 >> 5, c0 = f0 & 31;
    const int r1 = f1 >> 5, c1 = f1 & 31;
    const u16* Ab = A + (size_t)m0 * K;
    const u16* Bb = Bt + (size_t)n0 * K;

    floatx4 acc[4][4] = {};

    for (int kt = 0; kt < K; kt += 32) {
        async_ld16(Ab + (size_t)r0 * K + kt + c0, &As[f0]);
        async_ld16(Ab + (size_t)r1 * K + kt + c1, &As[f1]);
        async_ld16(Bb + (size_t)r0 * K + kt + c0, &Bs[f0]);
        async_ld16(Bb + (size_t)r1 * K + kt + c1, &Bs[f1]);
        __syncthreads();
        short8 af[4], bf[4];
#pragma unroll
        for (int i = 0; i < 4; ++i)
            af[i] = *(const short8*)&As[(wr * 64 + i * 16 + l16) * 32 + quad * 8];
#pragma unroll
        for (int j = 0; j < 4; ++j)
            bf[j] = *(const short8*)&Bs[(wc * 64 + j * 16 + l16) * 32 + quad * 8];
#pragma unroll
        for (int i = 0; i < 4; ++i)
#pragma unroll
            for (int j = 0; j < 4; ++j)
                acc[i][j] = __builtin_amdgcn_mfma_f32_16x16x32_bf16(af[i], bf[j], acc[i][j], 0, 0, 0);
        __syncthreads();
    }

    // ---- epilogue phase A: acc (+bias) -> bf16 into padded LDS stage ----
#pragma unroll
    for (int j = 0; j < 4; ++j) {
        const int col = wc * 64 + j * 16 + l16;
        const float bv = bias[n0 + col];
#pragma unroll
        for (int i = 0; i < 4; ++i)
#pragma unroll
            for (int r = 0; r < 4; ++r) {
                const int row = wr * 64 + i * 16 + quad * 4 + r;
                smem[row * 136 + col] = f2bf(acc[i][j][r] + bv);
            }
    }
    __syncthreads();

    // ---- epilogue phase B: cooperative coalesced writeout ----
    if (n0 < 1024) {
        // Q or K planes: [bh][49][32]; 16B chunks, 64B-line aligned.
        const int c   = n0 >> 9;
        const int hh0 = (n0 & 511) >> 5;
        u16* base = qkvp + (size_t)c * QTOT;
#pragma unroll
        for (int it = 0; it < 8; ++it) {
            const int idx  = it * 256 + tid;      // 0..2047
            const int row  = idx >> 4;
            const int hb   = (idx >> 2) & 3;
            const int part = idx & 3;
            short8 v = *(const short8*)&smem[row * 136 + hb * 32 + part * 8];
            const int rg = m0 + row;
            const int b2 = (int)((unsigned)rg / 49u);
            const int s  = rg - b2 * 49;
            *(short8*)(base + (size_t)(b2 * 16 + hh0 + hb) * 1568 + s * 32 + part * 8) = v;
        }
    } else {
        // V^T planes: [bh][32 d][64 s]; lanes along s (contiguous dst runs).
        const int hh0 = (n0 - 1024) >> 5;
        u16* base = qkvp + VOFF;
#pragma unroll 16
        for (int it = 0; it < 64; ++it) {
            const int idx = it * 256 + tid;       // 0..16383
            const int col = idx >> 7;             // 0..127 (tile col = head*32+d)
            const int row = idx & 127;
            const u16 v = smem[row * 136 + col];
            const int rg = m0 + row;
            const int b2 = (int)((unsigned)rg / 49u);
            const int s  = rg - b2 * 49;
            const int hh = hh0 + (col >> 5);
            const int d  = col & 31;
            base[(size_t)(b2 * 16 + hh) * 2048 + d * 64 + s] = v;
        }
    }
}

// ---------- GEMM: C[M][N] = A[M][K](bf16) * Bt[N][K]^T + bias (f32 out) ----------
__global__ __launch_bounds__(256, 2)
void gemm_bt(const u16* __restrict__ A, const u16* __restrict__ Bt,
             const float* __restrict__ bias, float* __restrict__ Cout,
             int M, int N, int K) {
    const int tid  = threadIdx.x;
    const int lane = tid & 63, wave = tid >> 6;
    const int quad = lane >> 4, l16 = lane & 15;
    const int wr = wave >> 1, wc = wave & 1;

    // XCD-bijective swizzle (applied when grid divides by 8).
    const int nbx = gridDim.x, nby = gridDim.y;
    const int total = nbx * nby;
    const int flat = blockIdx.y * nbx + blockIdx.x;
    const int swz = ((total & 7) == 0) ? ((flat & 7) * (total >> 3) + (flat >> 3)) : flat;
    const int bx = swz % nbx;
    const int by = swz / nbx;
    const int m0 = by * 128, n0 = bx * 128;

    __shared__ u16 As[128 * 32];
    __shared__ u16 Bs[128 * 32];

    const int f0 = (wave * 2 + 0) * 512 + lane * 8;
    const int f1 = (wave * 2 + 1) * 512 + lane * 8;
    const int r0 = f0 >> 5, c0 = f0 & 31;
    const int r1 = f1 >> 5, c1 = f1 & 31;
    const u16* Ab = A + (size_t)m0 * K;
    const u16* Bb = Bt + (size_t)n0 * K;

    floatx4 acc[4][4] = {};

    for (int kt = 0; kt < K; kt += 32) {
        async_ld16(Ab + (size_t)r0 * K + kt + c0, &As[f0]);
        async_ld16(Ab + (size_t)r1 * K + kt + c1, &As[f1]);
        async_ld16(Bb + (size_t)r0 * K + kt + c0, &Bs[f0]);
        async_ld16(Bb + (size_t)r1 * K + kt + c1, &Bs[f1]);
        __syncthreads();
        short8 af[4], bf[4];
#pragma unroll
        for (int i = 0; i < 4; ++i)
            af[i] = *(const short8*)&As[(wr * 64 + i * 16 + l16) * 32 + quad * 8];
#pragma unroll
        for (int j = 0; j < 4; ++j)
            bf[j] = *(const short8*)&Bs[(wc * 64 + j * 16 + l16) * 32 + quad * 8];
#pragma unroll
        for (int i = 0; i < 4; ++i)
#pragma unroll
            for (int j = 0; j < 4; ++j)
                acc[i][j] = __builtin_amdgcn_mfma_f32_16x16x32_bf16(af[i], bf[j], acc[i][j], 0, 0, 0);
        __syncthreads();
    }

#pragma unroll
    for (int i = 0; i < 4; ++i) {
#pragma unroll
        for (int j = 0; j < 4; ++j) {
            int col = n0 + wc * 64 + j * 16 + l16;
            float bv = bias[col];
#pragma unroll
            for (int r = 0; r < 4; ++r) {
                int row = m0 + wr * 64 + i * 16 + quad * 4 + r;
                Cout[(size_t)row * N + col] = acc[i][j][r] + bv;
            }
        }
    }
}

// ---------- attention: swapped QK^T, in-register softmax, no LDS ----------
// One wave per 2 (b,h) pairs. S^T = mfma(K_i, Q_j): lane l16 owns query row
// j*16+l16; keys i*16+quad*4+r live in regs. Row reduce = in-lane + 2 shfl.
// PV A-frags assembled by cross-quad __shfl (16 per j). Outputs of both pairs
// packed in regs and stored together (one write per 128B line).
__global__ __launch_bounds__(64, 4)
void attn2(const u16* __restrict__ qkvp, const float* __restrict__ cmbp,
           u16* __restrict__ out) {
    const int lane = threadIdx.x;
    const int quad = lane >> 4, l16 = lane & 15;
    const int p0 = blockIdx.x * 2;                 // pairs p0, p0+1 (same b, h0 even)
    const int b  = p0 >> 4, h0 = p0 & 15;

    const u16* qb0 = qkvp + (size_t)p0 * 1568;
    const u16* kb0 = qb0 + QTOT;
    const u16* vb0 = qkvp + VOFF + (size_t)p0 * 2048;   // V^T [32][64]
    const float* cb0 = cmbp + (size_t)((b & 63) * 16 + h0) * 49 * 64;

    u16* op0 = out + (size_t)b * SEQ * DIM + h0 * HD;
    u16* op1 = op0 + HD;

    const float scale2 = 0.2550348754f;            // 32^-0.5 * log2(e)

    // packed bf16 outputs: ob[pair][j][n][w] (w: rows {0,1} / {2,3})
    unsigned ob0[4][2][2], ob1[4][2][2];

    auto run_pair = [&](const u16* qb, const u16* kb, const u16* vb,
                        const float* cbp, unsigned (&ob)[4][2][2]) {
        // K as MFMA A-operand: kf[i] = K rows i*16+l16 (clamped), d = quad*8..+8
        short8 kf[4];
#pragma unroll
        for (int i = 0; i < 4; ++i) {
            int rk = i * 16 + l16; if (rk > 48) rk = 48;
            kf[i] = *(const short8*)(kb + rk * 32 + quad * 8);
        }
        // V^T as B-operand: vf[kt][n] = d-row n*16+l16, keys kt*32+quad*8..+8
        short8 vf[2][2];
#pragma unroll
        for (int kt = 0; kt < 2; ++kt)
#pragma unroll
            for (int n = 0; n < 2; ++n)
                vf[kt][n] = *(const short8*)(vb + (n * 16 + l16) * 64 + kt * 32 + quad * 8);

#pragma unroll
        for (int j = 0; j < 4; ++j) {
            const int q  = j * 16 + l16;
            const int rc = q < 49 ? q : 48;        // clamp (pad queries discarded)
            const short8 qf = *(const short8*)(qb + rc * 32 + quad * 8);

            // S^T tiles: accT[i][r] = S[q][k = i*16+quad*4+r]
            floatx4 accT[4] = {};
#pragma unroll
            for (int i = 0; i < 4; ++i)
                accT[i] = __builtin_amdgcn_mfma_f32_16x16x32_bf16(kf[i], qf, accT[i], 0, 0, 0);

            // logits + row max (in-lane 16 values, then 2 shuffles across quads)
            float x[4][4];
            float m = -3.0e38f;
#pragma unroll
            for (int i = 0; i < 4; ++i) {
                float4 c4 = *(const float4*)(cbp + rc * 64 + i * 16 + quad * 4);
                x[i][0] = accT[i][0] * scale2 + c4.x;
                x[i][1] = accT[i][1] * scale2 + c4.y;
                x[i][2] = accT[i][2] * scale2 + c4.z;
                x[i][3] = accT[i][3] * scale2 + c4.w;
                m = fmaxf(m, fmaxf(fmaxf(x[i][0], x[i][1]), fmaxf(x[i][2], x[i][3])));
            }
            m = fmaxf(m, __shfl_xor(m, 16));
            m = fmaxf(m, __shfl_xor(m, 32));

            float s = 0.f;
#pragma unroll
            for (int i = 0; i < 4; ++i)
#pragma unroll
                for (int r = 0; r < 4; ++r) {
                    float e = __builtin_amdgcn_exp2f(x[i][r] - m);
                    x[i][r] = e; s += e;
                }
            s += __shfl_xor(s, 16);
            s += __shfl_xor(s, 32);
            const float inv = __builtin_amdgcn_rcpf(s);

            // normalized P -> packed bf16: pk[i][w] = P[q][k=i*16+quad*4+{2w,2w+1}]
            unsigned pk[4][2];
#pragma unroll
            for (int i = 0; i < 4; ++i) {
                pk[i][0] = (unsigned)f2bf(x[i][0] * inv) | ((unsigned)f2bf(x[i][1] * inv) << 16);
                pk[i][1] = (unsigned)f2bf(x[i][2] * inv) | ((unsigned)f2bf(x[i][3] * inv) << 16);
            }

            // PV: assemble A-frags (row q, k = kt*32+quad*8+t) by cross-quad shfl
            floatx4 accO[2] = {};
#pragma unroll
            for (int kt = 0; kt < 2; ++kt) {
                u32x4 w;
#pragma unroll
                for (int W = 0; W < 4; ++W) {
                    const int src = (((quad & 1) * 2 + (W >> 1)) << 4) + l16;
                    const unsigned lo = (unsigned)__shfl((int)pk[2 * kt + 0][W & 1], src);
                    const unsigned hi = (unsigned)__shfl((int)pk[2 * kt + 1][W & 1], src);
                    w[W] = (quad & 2) ? hi : lo;
                }
                const short8 pa = __builtin_bit_cast(short8, w);
#pragma unroll
                for (int n = 0; n < 2; ++n)
                    accO[n] = __builtin_amdgcn_mfma_f32_16x16x32_bf16(pa, vf[kt][n], accO[n], 0, 0, 0);
            }
            // pack output tile j: O[q=j*16+quad*4+r][d=n*16+l16]
#pragma unroll
            for (int n = 0; n < 2; ++n) {
                ob[j][n][0] = (unsigned)f2bf(accO[n][0]) | ((unsigned)f2bf(accO[n][1]) << 16);
                ob[j][n][1] = (unsigned)f2bf(accO[n][2]) | ((unsigned)f2bf(accO[n][3]) << 16);
            }
        }
    };

    run_pair(qb0,        kb0,        vb0,        cb0,           ob0);
    run_pair(qb0 + 1568, kb0 + 1568, vb0 + 2048, cb0 + 49 * 64, ob1);

    // merged store: per row, heads h0 and h0+1 written back-to-back
    // (4 x 32B chunks = one 128B line per quad-row)
#pragma unroll
    for (int j = 0; j < 4; ++j)
#pragma unroll
        for (int r = 0; r < 4; ++r) {
            const int row = j * 16 + quad * 4 + r;
            if (row < SEQ) {
#pragma unroll
                for (int n = 0; n < 2; ++n) {
                    const unsigned w = ob0[j][n][r >> 1];
                    op0[(size_t)row * DIM + n * 16 + l16] =
                        (u16)((r & 1) ? (w >> 16) : (w & 0xffffu));
                }
#pragma unroll
                for (int n = 0; n < 2; ++n) {
                    const unsigned w = ob1[j][n][r >> 1];
                    op1[(size_t)row * DIM + n * 16 + l16] =
                        (u16)((r & 1) ? (w >> 16) : (w & 0xffffu));
                }
            }
        }
}

extern "C" void kernel_launch(void* const* d_in, const int* in_sizes, int n_in,
                              void* d_out, int out_size, void* d_ws, size_t ws_size,
                              hipStream_t stream) {
    const float* x         = (const float*)d_in[0];
    const float* mask      = (const float*)d_in[1];
    const float* qkv_w     = (const float*)d_in[2];
    const float* qkv_b     = (const float*)d_in[3];
    const float* proj_w    = (const float*)d_in[4];
    const float* proj_b    = (const float*)d_in[5];
    const float* bias_tab  = (const float*)d_in[6];
    const int*   rel_idx   = (const int*)d_in[7];
    float* out = (float*)d_out;

    char* ws = (char*)d_ws;
    u16*   xbf     = (u16*)(ws + 0);               // reused as attn_out
    u16*   qkvp    = (u16*)(ws + 102760448);
    u16*   wqkv_t  = (u16*)(ws + 452333568);
    u16*   wproj_t = (u16*)(ws + 453906432);
    // natural-layout padded combined table lives in d_out (scratch until gemm_bt):
    float* cmb     = out;                          // 64*16*49*64 f32 = 12.8 MB

    // x -> bf16 (51,380,224 elems = 12,845,056 float4s)
    conv_f32_bf16<<<50176, 256, 0, stream>>>(x, xbf, 12845056);
    // weight transposes
    transpose_conv<<<3072, 256, 0, stream>>>(qkv_w, wqkv_t, 1536);
    transpose_conv<<<1024, 256, 0, stream>>>(proj_w, wproj_t, 512);
    // natural padded combined bias+mask table (x log2e) -> d_out scratch
    build_combined<<<12544, 256, 0, stream>>>(mask, bias_tab, rel_idx, cmb);
    // zero V^T pad rows (s in [48,64)) before gemm_qkv rewrites s=48
    zero_vpad<<<4096, 256, 0, stream>>>(qkvp);
    // qkv GEMM -> scattered per-head planes (merged again)
    gemm_qkv<<<dim3(12, 784), 256, 0, stream>>>(xbf, wqkv_t, qkv_b, qkvp);
    // attention (2 pairs per wave, register softmax) -> attn_out (reuses xbf)
    attn2<<<B_WIN * NHEAD / 2, 64, 0, stream>>>(qkvp, cmb, xbf);
    // out = attn @ proj_w + proj_b (overwrites the cmb scratch)
    gemm_bt<<<dim3(4, 784), 256, 0, stream>>>(xbf, wproj_t, proj_b, out,
                                              MROWS, 512, 512);
}